// Round 9
// baseline (41.574 us; speedup 1.0000x reference)
//
#include <hip/hip_runtime.h>

// D-FINE post-processor, two kernels, segmented candidate lists (no global
// atomics, no memset, fully deterministic):
//   K1 (filter): B*BPB blocks; block (b,slice) owns a 2000-float4 slice and a
//       PRIVATE segment of candG. ONE load burst (8 float4/thread, clamped,
//       sched_barrier) + one consume pass: hits (logit > THR) scatter into the
//       segment at an LDS-counter offset; count written to scnt[blk].
//   K2 (select): one block per batch; reads 10 segment counts, prefix-sums,
//       bound-checks (m_s <= SEG, K <= total <= CAPL), loads segments into LDS,
//       BITONIC-SORTS the packed (key<<32)|~idx candidates descending (exact
//       jax.lax.top_k tie semantics: equal keys -> lowest index first), then
//       emits the first K in order (coalesced). Exact histogram FALLBACK over
//       the batch if the bound check fails.
// {x > THR} is a prefix of the descending score order, so when the bound check
// passes the candidate set provably contains the top-K.
// Output (float32): labels [B*K] | boxes [B*K*4] | scores [B*K]

constexpr int   NT1   = 256;    // filter block
constexpr int   BPB   = 10;     // filter blocks (segments) per batch; chunk=2000
constexpr int   UN    = 8;      // float4 loads in flight per thread (2048 >= 2000)
constexpr int   SEG   = 512;    // slots per segment (expected ~66 hits)
constexpr int   NT2   = 1024;   // select block
constexpr int   NBINS = 4096;
constexpr int   CAPL  = 4096;   // per-batch candidate cap in LDS (select)
constexpr float THR   = 2.4f;   // static pre-filter (fallback makes it safe)

__device__ __forceinline__ unsigned f2key(float f) {
    unsigned u = __float_as_uint(f);
    return (u & 0x80000000u) ? ~u : (u | 0x80000000u);
}
__device__ __forceinline__ float key2f(unsigned k) {
    unsigned u = (k & 0x80000000u) ? (k & 0x7FFFFFFFu) : ~k;
    return __uint_as_float(u);
}
__device__ __forceinline__ unsigned long long packkv(unsigned key, unsigned idx) {
    return ((unsigned long long)key << 32) | (unsigned long long)(0xFFFFFFFFu - idx);
}

// ---------------- Kernel 1: single-sweep filter into private segments ----------------
__global__ __launch_bounds__(NT1) void dfine_filter_kernel(
    const float4* __restrict__ lg4,          // [B * N4]
    unsigned* __restrict__ scnt,             // [B * BPB]  (overwritten each call)
    unsigned long long* __restrict__ candG,  // [B * BPB * seg]
    int N4, int seg)
{
    const int blk   = blockIdx.x;
    const int b     = blk / BPB;
    const int slice = blk - b * BPB;
    const int chunk = (N4 + BPB - 1) / BPB;          // 2000
    const int lo    = slice * chunk;
    const int hi    = (lo + chunk < N4) ? (lo + chunk) : N4;
    const float4* __restrict__ base4 = lg4 + (long long)b * N4;
    unsigned long long* __restrict__ segp = candG + (long long)blk * seg;

    __shared__ unsigned lcnt;
    if (threadIdx.x == 0) lcnt = 0u;
    __syncthreads();

    // ONE burst: all UN loads issued before any consume (chunk <= UN*NT1)
    float4 v[UN];
    #pragma unroll
    for (int j = 0; j < UN; ++j) {
        int i4 = lo + j * NT1 + threadIdx.x;
        int c  = (i4 < hi) ? i4 : (hi - 1);          // clamped load, predicated use
        v[j] = base4[c];
    }
    __builtin_amdgcn_sched_barrier(0);               // keep all UN loads in flight
    #pragma unroll
    for (int j = 0; j < UN; ++j) {
        int i4 = lo + j * NT1 + threadIdx.x;
        if (i4 < hi) {
            float mx = fmaxf(fmaxf(v[j].x, v[j].y), fmaxf(v[j].z, v[j].w));
            if (mx > THR) {
                unsigned bi = (unsigned)(4 * i4);
                if (v[j].x > THR) { unsigned p = atomicAdd(&lcnt, 1u);
                    if (p < (unsigned)seg) segp[p] = packkv(f2key(v[j].x), bi + 0); }
                if (v[j].y > THR) { unsigned p = atomicAdd(&lcnt, 1u);
                    if (p < (unsigned)seg) segp[p] = packkv(f2key(v[j].y), bi + 1); }
                if (v[j].z > THR) { unsigned p = atomicAdd(&lcnt, 1u);
                    if (p < (unsigned)seg) segp[p] = packkv(f2key(v[j].z), bi + 2); }
                if (v[j].w > THR) { unsigned p = atomicAdd(&lcnt, 1u);
                    if (p < (unsigned)seg) segp[p] = packkv(f2key(v[j].w), bi + 3); }
            }
        }
    }
    __syncthreads();
    if (threadIdx.x == 0) scnt[blk] = lcnt;          // true count (may exceed seg -> fallback)
}

// ---------------- Kernel 2: per-batch bitonic-sort select + emit ----------------
__global__ __launch_bounds__(NT2) void dfine_select_kernel(
    const float* __restrict__ logits,              // [B, N] (fallback only)
    const float* __restrict__ pboxes,              // [B, Q, 4]
    const float* __restrict__ sizes,               // [B, 2]
    const unsigned* __restrict__ scnt,             // [B * BPB]
    const unsigned long long* __restrict__ candG,  // [B * BPB * seg]
    float* __restrict__ out,
    int B, int Q, int C, int K, int seg)
{
    const int b   = blockIdx.x;
    const int tid = threadIdx.x;
    const int N   = Q * C;

    __shared__ unsigned long long cand[CAPL];
    __shared__ unsigned hist[NBINS];
    __shared__ unsigned partial[NT2];
    __shared__ unsigned msz[BPB], moff[BPB];
    __shared__ unsigned candCount;
    __shared__ unsigned threshBin;
    __shared__ int hot;

    if (tid < BPB) msz[tid] = scnt[b * BPB + tid];
    __syncthreads();
    if (tid == 0) {
        unsigned tot = 0; int ok = 1;
        #pragma unroll
        for (int s = 0; s < BPB; ++s) {
            moff[s] = tot;
            if (msz[s] > (unsigned)seg) ok = 0;
            tot += msz[s];
        }
        candCount = tot;
        hot = ok && tot >= (unsigned)K && tot <= (unsigned)CAPL;
    }
    __syncthreads();

    int n;
    if (hot) {
        // ---- hot path: copy segments compactly into LDS ----
        n = (int)candCount;
        #pragma unroll
        for (int s = 0; s < BPB; ++s) {
            const unsigned long long* sp = candG + (long long)(b * BPB + s) * seg;
            unsigned m = msz[s], o = moff[s];
            for (unsigned i = tid; i < m; i += NT2) cand[o + i] = sp[i];
        }
        __syncthreads();
    } else {
        // ---- fallback: exact histogram selection over the full batch ----
        const float* __restrict__ lg = logits + (long long)b * N;
        for (int i = tid; i < NBINS; i += NT2) hist[i] = 0u;
        if (tid == 0) candCount = 0u;
        __syncthreads();
        for (int i = tid; i < N; i += NT2)
            atomicAdd(&hist[f2key(lg[i]) >> 20], 1u);
        __syncthreads();
        {
            const int BPT = NBINS / NT2;
            unsigned s = 0;
            #pragma unroll
            for (int m = 0; m < BPT; ++m) s += hist[tid * BPT + m];
            partial[tid] = s;
        }
        __syncthreads();
        if (tid < 64) {
            const int PPG = NT2 / 64;
            unsigned gs = 0;
            #pragma unroll
            for (int m = 0; m < PPG; ++m) gs += partial[tid * PPG + m];
            unsigned pre = gs;
            #pragma unroll
            for (int off = 1; off < 64; off <<= 1) {
                unsigned t = __shfl_up(pre, off);
                if (tid >= off) pre += t;
            }
            unsigned total = __shfl(pre, 63);
            unsigned suf   = total - (pre - gs);
            unsigned long long m1 = __ballot(suf >= (unsigned)K);
            int g = 63 - __clzll(m1);
            unsigned above = total - __shfl(pre, g);
            unsigned hv = hist[g * 64 + tid];
            unsigned pre2 = hv;
            #pragma unroll
            for (int off = 1; off < 64; off <<= 1) {
                unsigned t = __shfl_up(pre2, off);
                if (tid >= off) pre2 += t;
            }
            unsigned total2 = __shfl(pre2, 63);
            unsigned suf2   = above + total2 - (pre2 - hv);
            unsigned long long m2 = __ballot(suf2 >= (unsigned)K);
            int l2 = 63 - __clzll(m2);
            if (tid == 0) threshBin = (unsigned)(g * 64 + l2);
        }
        __syncthreads();
        const unsigned tb = threshBin;
        if (tid == 0) candCount = 0u;
        __syncthreads();
        for (int i = tid; i < N; i += NT2) {
            unsigned k = f2key(lg[i]);
            if ((k >> 20) >= tb) {
                unsigned p = atomicAdd(&candCount, 1u);
                if (p < (unsigned)CAPL) cand[p] = packkv(k, (unsigned)i);
            }
        }
        __syncthreads();
        n = (int)min(candCount, (unsigned)CAPL);
    }

    // ---- bitonic sort descending on packed keys (padding 0 sinks) ----
    int P = 2;
    while (P < n) P <<= 1;                            // P <= CAPL
    for (int i = n + tid; i < P; i += NT2) cand[i] = 0ull;
    __syncthreads();
    for (int ksz = 2; ksz <= P; ksz <<= 1) {
        for (int j = ksz >> 1; j > 0; j >>= 1) {
            for (int i = tid; i < P; i += NT2) {
                int ixj = i ^ j;
                if (ixj > i) {
                    unsigned long long a = cand[i];
                    unsigned long long c = cand[ixj];
                    bool upper = ((i & ksz) == 0);
                    if (upper ? (a < c) : (a > c)) { cand[i] = c; cand[ixj] = a; }
                }
            }
            __syncthreads();
        }
    }

    // ---- emit top-K in sorted order (coalesced) ----
    const int BK = B * K;
    float* __restrict__ out_labels = out;
    float* __restrict__ out_boxes  = out + BK;
    float* __restrict__ out_scores = out + (long long)BK * 5;
    const float s0 = sizes[2 * b];
    const float s1 = sizes[2 * b + 1];

    for (int k = tid; k < K; k += NT2) {
        unsigned long long v = cand[k];
        unsigned key = (unsigned)(v >> 32);
        unsigned idx = 0xFFFFFFFFu - (unsigned)(v & 0xFFFFFFFFull);
        float logit = key2f(key);
        float score = 1.0f / (1.0f + expf(-logit));
        int label = (int)(idx % (unsigned)C);
        int q     = (int)(idx / (unsigned)C);
        float4 bp = *reinterpret_cast<const float4*>(pboxes + ((long long)b * Q + q) * 4);
        int o = b * K + k;
        out_labels[o] = (float)label;
        out_scores[o] = score;
        float4 bb;
        bb.x = (bp.x - 0.5f * bp.z) * s0;
        bb.y = (bp.y - 0.5f * bp.w) * s1;
        bb.z = (bp.x + 0.5f * bp.z) * s0;
        bb.w = (bp.y + 0.5f * bp.w) * s1;
        *reinterpret_cast<float4*>(out_boxes + 4LL * o) = bb;
    }
}

extern "C" void kernel_launch(void* const* d_in, const int* in_sizes, int n_in,
                              void* d_out, int out_size, void* d_ws, size_t ws_size,
                              hipStream_t stream) {
    const float* logits = (const float*)d_in[0];
    const float* pboxes = (const float*)d_in[1];
    const float* sizes  = (const float*)d_in[2];

    const int B = in_sizes[2] / 2;                 // 256
    const int Q = in_sizes[1] / (4 * B);           // 1000
    const int C = in_sizes[0] / (B * Q);           // 80
    const int K = out_size / (6 * B);              // 300
    const int N = Q * C;
    const int N4 = N / 4;
    const int NSEGS = B * BPB;

    // workspace layout: scnt[B*BPB] | candG[B*BPB*seg]   (no zeroing required)
    unsigned* scnt = (unsigned*)d_ws;
    size_t cand_off = (((size_t)NSEGS * sizeof(unsigned) + 255) & ~(size_t)255);
    unsigned long long* candG = (unsigned long long*)((char*)d_ws + cand_off);
    long long avail = (long long)ws_size - (long long)cand_off;
    int seg = (avail > 0) ? (int)(avail / ((long long)NSEGS * 8)) : 0;
    if (seg > SEG) seg = SEG;
    if (seg < 0) seg = 0;
    // seg too small => per-slice counts exceed seg => select falls back (correct)

    dfine_filter_kernel<<<NSEGS, NT1, 0, stream>>>(
        (const float4*)logits, scnt, candG, N4, seg);
    dfine_select_kernel<<<B, NT2, 0, stream>>>(
        logits, pboxes, sizes, scnt, candG, (float*)d_out, B, Q, C, K, seg);
}

// Round 10
// 33.465 us; speedup vs baseline: 1.2423x; 1.2423x over previous
//
#include <hip/hip_runtime.h>

// D-FINE post-processor, SINGLE fused kernel: one block per batch (256 x 1024).
//   Filter: three explicit loop-free burst phases (7+7+6 float4/thread,
//     loads fully issued before sched_barrier -> real MLP, nothing for the
//     compiler to jam). Hits (logit > THR) compact into LDS cand[] via an LDS
//     counter. {x > THR} is a prefix of the descending order, so if
//     K <= n <= CAPL the top-K is provably contained.
//   Select: rank-based (count-of-greater over packed (key<<32)|~idx keys =
//     exact jax.lax.top_k tie semantics, broadcast LDS reads), scatter-emit
//     by rank. Deterministic regardless of compaction order.
//   Fallback: exact in-kernel 4096-bin histogram selection if the bound check
//     fails (any input distribution stays correct).
// Output (float32): labels [B*K] | boxes [B*K*4] | scores [B*K]

constexpr int   NT    = 1024;
constexpr int   NBINS = 4096;
constexpr int   CAPL  = 4096;   // LDS candidate capacity
constexpr float THR   = 2.4f;   // static pre-filter (fallback makes it safe)

__device__ __forceinline__ unsigned f2key(float f) {
    unsigned u = __float_as_uint(f);
    return (u & 0x80000000u) ? ~u : (u | 0x80000000u);
}
__device__ __forceinline__ float key2f(unsigned k) {
    unsigned u = (k & 0x80000000u) ? (k & 0x7FFFFFFFu) : ~k;
    return __uint_as_float(u);
}
__device__ __forceinline__ unsigned long long packkv(unsigned key, unsigned idx) {
    return ((unsigned long long)key << 32) | (unsigned long long)(0xFFFFFFFFu - idx);
}

template<int UNROLL>
__device__ __forceinline__ void filter_phase(
    const float4* __restrict__ base4, int start, int N4,
    unsigned* lcnt, unsigned long long* cand, int tid)
{
    float4 v[UNROLL];
    #pragma unroll
    for (int j = 0; j < UNROLL; ++j) {
        int i4 = start + j * NT + tid;
        int c  = (i4 < N4) ? i4 : (N4 - 1);          // clamped load, predicated use
        v[j] = base4[c];
    }
    __builtin_amdgcn_sched_barrier(0);               // all UNROLL loads in flight
    #pragma unroll
    for (int j = 0; j < UNROLL; ++j) {
        int i4 = start + j * NT + tid;
        if (i4 < N4) {
            float4 x = v[j];
            float mx = fmaxf(fmaxf(x.x, x.y), fmaxf(x.z, x.w));
            if (mx > THR) {
                unsigned bi = (unsigned)(4 * i4);
                if (x.x > THR) { unsigned p = atomicAdd(lcnt, 1u);
                    if (p < (unsigned)CAPL) cand[p] = packkv(f2key(x.x), bi + 0); }
                if (x.y > THR) { unsigned p = atomicAdd(lcnt, 1u);
                    if (p < (unsigned)CAPL) cand[p] = packkv(f2key(x.y), bi + 1); }
                if (x.z > THR) { unsigned p = atomicAdd(lcnt, 1u);
                    if (p < (unsigned)CAPL) cand[p] = packkv(f2key(x.z), bi + 2); }
                if (x.w > THR) { unsigned p = atomicAdd(lcnt, 1u);
                    if (p < (unsigned)CAPL) cand[p] = packkv(f2key(x.w), bi + 3); }
            }
        }
    }
}

__global__ __launch_bounds__(NT) void dfine_fused_kernel(
    const float* __restrict__ logits,   // [B, Q*C]
    const float* __restrict__ pboxes,   // [B, Q, 4]  (cx, cy, w, h)
    const float* __restrict__ sizes,    // [B, 2]
    float* __restrict__ out,            // labels | boxes | scores
    int B, int Q, int C, int K)
{
    const int b   = blockIdx.x;
    const int tid = threadIdx.x;
    const int N   = Q * C;
    const int N4  = N >> 2;             // N divisible by 4 (C=80)
    const float4* __restrict__ base4 = reinterpret_cast<const float4*>(logits + (long long)b * N);

    __shared__ unsigned long long cand[CAPL];   // 32 KB
    __shared__ unsigned hist[NBINS];            // 16 KB (fallback only)
    __shared__ unsigned partial[NT];            //  4 KB (fallback only)
    __shared__ unsigned lcnt;
    __shared__ unsigned candCount;
    __shared__ unsigned threshBin;

    if (tid == 0) lcnt = 0u;
    __syncthreads();

    // ---- filter: three loop-free burst phases (cover N4 <= 20*NT) ----
    filter_phase<7>(base4, 0,       N4, &lcnt, cand, tid);
    filter_phase<7>(base4, 7 * NT,  N4, &lcnt, cand, tid);
    filter_phase<6>(base4, 14 * NT, N4, &lcnt, cand, tid);
    // generic tail for hypothetical larger shapes (no-op at N4 = 20000)
    for (int i4 = 20 * NT + tid; i4 < N4; i4 += NT) {
        float4 x = base4[i4];
        float mx = fmaxf(fmaxf(x.x, x.y), fmaxf(x.z, x.w));
        if (mx > THR) {
            unsigned bi = (unsigned)(4 * i4);
            if (x.x > THR) { unsigned p = atomicAdd(&lcnt, 1u);
                if (p < (unsigned)CAPL) cand[p] = packkv(f2key(x.x), bi + 0); }
            if (x.y > THR) { unsigned p = atomicAdd(&lcnt, 1u);
                if (p < (unsigned)CAPL) cand[p] = packkv(f2key(x.y), bi + 1); }
            if (x.z > THR) { unsigned p = atomicAdd(&lcnt, 1u);
                if (p < (unsigned)CAPL) cand[p] = packkv(f2key(x.z), bi + 2); }
            if (x.w > THR) { unsigned p = atomicAdd(&lcnt, 1u);
                if (p < (unsigned)CAPL) cand[p] = packkv(f2key(x.w), bi + 3); }
        }
    }
    __syncthreads();

    int n;
    const unsigned tot = lcnt;
    if (tot >= (unsigned)K && tot <= (unsigned)CAPL) {
        n = (int)tot;                               // hot path: cand[] already in LDS
    } else {
        // ---- fallback: exact histogram selection over the full batch ----
        const float* __restrict__ lg = logits + (long long)b * N;
        for (int i = tid; i < NBINS; i += NT) hist[i] = 0u;
        if (tid == 0) candCount = 0u;
        __syncthreads();
        for (int i = tid; i < N; i += NT)
            atomicAdd(&hist[f2key(lg[i]) >> 20], 1u);
        __syncthreads();
        {
            const int BPT = NBINS / NT;
            unsigned s = 0;
            #pragma unroll
            for (int m = 0; m < BPT; ++m) s += hist[tid * BPT + m];
            partial[tid] = s;
        }
        __syncthreads();
        if (tid < 64) {
            const int PPG = NT / 64;
            unsigned gs = 0;
            #pragma unroll
            for (int m = 0; m < PPG; ++m) gs += partial[tid * PPG + m];
            unsigned pre = gs;
            #pragma unroll
            for (int off = 1; off < 64; off <<= 1) {
                unsigned t = __shfl_up(pre, off);
                if (tid >= off) pre += t;
            }
            unsigned total = __shfl(pre, 63);
            unsigned suf   = total - (pre - gs);
            unsigned long long m1 = __ballot(suf >= (unsigned)K);
            int g = 63 - __clzll(m1);
            unsigned above = total - __shfl(pre, g);
            unsigned hv = hist[g * 64 + tid];
            unsigned pre2 = hv;
            #pragma unroll
            for (int off = 1; off < 64; off <<= 1) {
                unsigned t = __shfl_up(pre2, off);
                if (tid >= off) pre2 += t;
            }
            unsigned total2 = __shfl(pre2, 63);
            unsigned suf2   = above + total2 - (pre2 - hv);
            unsigned long long m2 = __ballot(suf2 >= (unsigned)K);
            int l2 = 63 - __clzll(m2);
            if (tid == 0) threshBin = (unsigned)(g * 64 + l2);
        }
        __syncthreads();
        const unsigned tb = threshBin;
        for (int i = tid; i < N; i += NT) {
            unsigned k = f2key(lg[i]);
            if ((k >> 20) >= tb) {
                unsigned p = atomicAdd(&candCount, 1u);
                if (p < (unsigned)CAPL) cand[p] = packkv(k, (unsigned)i);
            }
        }
        __syncthreads();
        n = (int)min(candCount, (unsigned)CAPL);
    }

    // ---- rank-based selection + emit ----
    const int BK = B * K;
    float* __restrict__ out_labels = out;
    float* __restrict__ out_boxes  = out + BK;
    float* __restrict__ out_scores = out + (long long)BK * 5;
    const float s0 = sizes[2 * b];
    const float s1 = sizes[2 * b + 1];

    for (int t = tid; t < n; t += NT) {
        unsigned long long my = cand[t];
        int r = 0;
        for (int j = 0; j < n; ++j) r += (cand[j] > my);   // packed keys unique
        if (r < K) {
            unsigned key = (unsigned)(my >> 32);
            unsigned idx = 0xFFFFFFFFu - (unsigned)(my & 0xFFFFFFFFull);
            float logit = key2f(key);
            float score = 1.0f / (1.0f + expf(-logit));
            int label = (int)(idx % (unsigned)C);
            int q     = (int)(idx / (unsigned)C);
            float4 bp = *reinterpret_cast<const float4*>(pboxes + ((long long)b * Q + q) * 4);
            int o = b * K + r;
            out_labels[o] = (float)label;
            out_scores[o] = score;
            float4 bb;
            bb.x = (bp.x - 0.5f * bp.z) * s0;
            bb.y = (bp.y - 0.5f * bp.w) * s1;
            bb.z = (bp.x + 0.5f * bp.z) * s0;
            bb.w = (bp.y + 0.5f * bp.w) * s1;
            *reinterpret_cast<float4*>(out_boxes + 4LL * o) = bb;
        }
    }
}

extern "C" void kernel_launch(void* const* d_in, const int* in_sizes, int n_in,
                              void* d_out, int out_size, void* d_ws, size_t ws_size,
                              hipStream_t stream) {
    const float* logits = (const float*)d_in[0];
    const float* pboxes = (const float*)d_in[1];
    const float* sizes  = (const float*)d_in[2];

    const int B = in_sizes[2] / 2;                 // 256
    const int Q = in_sizes[1] / (4 * B);           // 1000
    const int C = in_sizes[0] / (B * Q);           // 80
    const int K = out_size / (6 * B);              // 300

    dfine_fused_kernel<<<B, NT, 0, stream>>>(
        logits, pboxes, sizes, (float*)d_out, B, Q, C, K);
}